// Round 9
// baseline (240.749 us; speedup 1.0000x reference)
//
#include <hip/hip_runtime.h>
#include <hip/hip_bf16.h>

// Problem constants (fixed by setup_inputs)
#define BS   4
#define NQ   6400
#define DIMS 256
#define NH   8
#define NP   4
#define GW   80
#define GH   80

typedef __hip_bfloat16 bf16;
typedef unsigned short ushort;
typedef __attribute__((ext_vector_type(8))) short short8;   // 8 bf16 (MFMA A/B frag)
typedef __attribute__((ext_vector_type(4))) float floatx4;  // MFMA C/D frag

union bfu { bf16 h; ushort s; };
__device__ __forceinline__ ushort f2bs(float x) { bfu u; u.h = __float2bfloat16(x); return u.s; }
__device__ __forceinline__ float bs2f(ushort s) { return __uint_as_float(((unsigned)s) << 16); }
__device__ __forceinline__ float ldin(const void* p, size_t i, int isf) {
    return isf ? ((const float*)p)[i] : bs2f(((const ushort*)p)[i]);
}

// ---------------------------------------------------------------------------
// prep: self-detecting fused input-convert + weight transpose/convert.
// Each block detects dtype itself (f32 read as bf16 -> impossible exponents in
// the first 256 half-words of query; P(miss) ~ 1e-13). Block 0 publishes flag.
// blocks [0,6400): query/voxbev -> bf16 (skip if already bf16)
// blocks [6400,7299): weights -> bf16 B^T[n][k]; biases -> f32
// ---------------------------------------------------------------------------
__global__ __launch_bounds__(256) void prep_k(
    const void* __restrict__ query, const void* __restrict__ voxbev,
    const void* __restrict__ Wv, const void* __restrict__ bv,
    const void* __restrict__ Woff, const void* __restrict__ boff,
    const void* __restrict__ Wattn, const void* __restrict__ battn,
    const void* __restrict__ Wo, const void* __restrict__ bo,
    int* __restrict__ flagp,
    uint4* __restrict__ qb, uint4* __restrict__ vbv,
    ushort* __restrict__ WvT, ushort* __restrict__ WoaT, ushort* __restrict__ WoT,
    float* __restrict__ biasv, float* __restrict__ biasoa, float* __restrict__ biaso)
{
    __shared__ int sflag;
    if (threadIdx.x == 0) sflag = 0;
    __syncthreads();
    {   // self-detect on first 256 half-words of query
        const ushort v = ((const ushort*)query)[threadIdx.x];
        const int e = (v >> 7) & 0xFF;
        if (e > 160) atomicOr(&sflag, 1);
    }
    __syncthreads();
    const int isf = sflag;
    if (blockIdx.x == 0 && threadIdx.x == 0) *flagp = isf;

    if (blockIdx.x < 6400) {
        if (!isf) return;
        const int t = blockIdx.x * 256 + threadIdx.x;
        const int half = 819200;
        const void* src = (t < half) ? query : voxbev;
        uint4* dst = (t < half) ? qb : vbv;
        const int j = (t < half) ? t : t - half;
        const float4* s = (const float4*)src + (size_t)j * 2;
        float4 a = s[0], b = s[1];
        uint4 o;
        o.x = ((unsigned)f2bs(a.y) << 16) | f2bs(a.x);
        o.y = ((unsigned)f2bs(a.w) << 16) | f2bs(a.z);
        o.z = ((unsigned)f2bs(b.y) << 16) | f2bs(b.x);
        o.w = ((unsigned)f2bs(b.w) << 16) | f2bs(b.z);
        dst[j] = o;
        return;
    }
    const int i = (blockIdx.x - 6400) * 256 + threadIdx.x;
    const int n1 = 256 * 256, n2 = n1 + 192 * 512, n3 = n2 + 256 * 256;
    const int n4 = n3 + 256, n5 = n4 + 192, n6 = n5 + 256;
    if (i < n1) {
        int n = i >> 8, k = i & 255;
        WvT[i] = f2bs(ldin(Wv, (size_t)k * 256 + n, isf));
    } else if (i < n2) {
        int j = i - n1, n = j >> 9, k = j & 511;
        float v = (n < 128) ? ldin(Woff, (size_t)k * 128 + n, isf)
                            : ldin(Wattn, (size_t)k * 64 + (n - 128), isf);
        WoaT[j] = f2bs(v);
    } else if (i < n3) {
        int j = i - n2, n = j >> 8, k = j & 255;
        WoT[j] = f2bs(ldin(Wo, (size_t)k * 256 + n, isf));
    } else if (i < n4) {
        biasv[i - n3] = ldin(bv, i - n3, isf);
    } else if (i < n5) {
        int j = i - n4;
        biasoa[j] = (j < 128) ? ldin(boff, j, isf) : ldin(battn, j - 128, isf);
    } else if (i < n6) {
        biaso[i - n5] = ldin(bo, i - n5, isf);
    }
}

// ---------------------------------------------------------------------------
// Barrier-free, LDS-free wave-GEMM:
//  - Block = 64 rows x NTOT cols; wave = 32 rows x NW cols. ZERO __syncthreads.
//  - A AND B fragments loaded directly from global in MFMA layout: per load
//    instr, lanes {r,r+16,r+32,r+48} consume full 64B sectors of 16 rows;
//    across the unrolled K-loop each touched row is fully consumed.
//    B (<=192KB) is L2-resident (re-reads hit L2 at ~14 TB/s aggregate).
//  - acc = 2 x NW/16 floatx4 (64 regs at NW=128) -> low pressure -> 3 w/SIMD.
//  - Epilogue: wave-PRIVATE LDS bounce (no barrier), full-line stores.
// AMODE: A_VAL interleaved value rows; A_QCAT [value|query] K=512; A_PLAIN flat.
// OMODE: O_BF16 bf16 out (+bias); O_FINAL +bias+bf16 residual, f32/bf16 per isf.
// ---------------------------------------------------------------------------
enum { A_VAL = 0, A_QCAT = 1, A_PLAIN = 2 };
enum { O_BF16 = 0, O_FINAL = 1 };

template <int AMODE, int OMODE, int NW, int KTOT, int NTOT>
__device__ __forceinline__ void gemmw(
    int bm, const ushort* __restrict__ Apl, const ushort* __restrict__ BT,
    const float* __restrict__ biasf, void* __restrict__ C,
    const ushort* __restrict__ qsrc, const ushort* __restrict__ vsrc,
    int isf, ushort* __restrict__ bounce)
{
    constexpr int NF = NW / 16;
    constexpr int NK = KTOT / 32;
    constexpr int BSTR = NW + 8;              // bounce row stride (shorts)
    const int tid = threadIdx.x, lane = tid & 63, wv = tid >> 6;
    const int rowb = bm + (wv & 1) * 32;      // wave's row base
    const int bcol = (wv >> 1) * NW;          // wave's col base
    const int fr = lane & 15, fq = (lane >> 4) * 8;

    // A row pointers (fq folded in)
    const ushort* a0; const ushort* a1;
    const ushort* a0h = nullptr; const ushort* a1h = nullptr;
    {
        const int r0 = rowb + fr, r1 = rowb + 16 + fr;
        if (AMODE == A_PLAIN) {
            a0 = Apl + (size_t)r0 * DIMS + fq;
            a1 = Apl + (size_t)r1 * DIMS + fq;
        } else {
            const int b = rowb / NQ;          // 64 | NQ: whole block same batch
            const ushort* base = (b & 1) ? vsrc : qsrc;
            const size_t ob = (size_t)((b >> 1) * NQ) * DIMS;
            a0 = base + ob + (size_t)(r0 - b * NQ) * DIMS + fq;
            a1 = base + ob + (size_t)(r1 - b * NQ) * DIMS + fq;
            if (AMODE == A_QCAT) {
                a0h = qsrc + ((size_t)b * NQ + (r0 - b * NQ)) * DIMS + fq;
                a1h = qsrc + ((size_t)b * NQ + (r1 - b * NQ)) * DIMS + fq;
            }
        }
    }
    const ushort* brow[NF];
    #pragma unroll
    for (int nf = 0; nf < NF; ++nf)
        brow[nf] = BT + (size_t)(bcol + nf * 16 + fr) * KTOT + fq;

    floatx4 acc[2][NF] = {};
    #pragma unroll
    for (int kk = 0; kk < NK; ++kk) {
        const int k0 = kk * 32;
        const bool hi = (AMODE == A_QCAT) && (k0 >= 256);
        const short8 af0 = *(const short8*)((hi ? a0h - 256 : a0) + k0);
        const short8 af1 = *(const short8*)((hi ? a1h - 256 : a1) + k0);
        short8 bf[NF];
        #pragma unroll
        for (int nf = 0; nf < NF; ++nf)
            bf[nf] = *(const short8*)(brow[nf] + k0);
        #pragma unroll
        for (int nf = 0; nf < NF; ++nf) {
            acc[0][nf] = __builtin_amdgcn_mfma_f32_16x16x32_bf16(af0, bf[nf], acc[0][nf], 0, 0, 0);
            acc[1][nf] = __builtin_amdgcn_mfma_f32_16x16x32_bf16(af1, bf[nf], acc[1][nf], 0, 0, 0);
        }
    }

    // ---- epilogue: wave-private bounce (no barrier).
    // C/D layout: col=lane&15, row=(lane>>4)*4+reg (m89-verified).
    ushort* wb = bounce + wv * 32 * BSTR;
    const int col = lane & 15, rq4 = (lane >> 4) * 4;
    float bvv[NF];
    #pragma unroll
    for (int nf = 0; nf < NF; ++nf) bvv[nf] = biasf[bcol + nf * 16 + col];
    #pragma unroll
    for (int mt = 0; mt < 2; ++mt)
        #pragma unroll
        for (int nf = 0; nf < NF; ++nf)
            #pragma unroll
            for (int r = 0; r < 4; ++r)
                wb[(mt * 16 + rq4 + r) * BSTR + nf * 16 + col] =
                    f2bs(acc[mt][nf][r] + bvv[nf]);

    if (OMODE == O_BF16) {
        // full-line stores: chunks of 8 shorts (16B)
        constexpr int CPR = NW / 8;           // chunks per row
        #pragma unroll
        for (int ch = 0; ch < 32 * CPR / 64; ++ch) {
            const int c = ch * 64 + lane;
            const int lr = c / CPR, cc = (c % CPR) * 8;
            const uint4 d = *(const uint4*)&wb[lr * BSTR + cc];
            *(uint4*)((ushort*)C + (size_t)(rowb + lr) * NTOT + bcol + cc) = d;
        }
    } else {
        // +residual (bf16 qsrc); store f32 (isf) or bf16
        constexpr int CPR = NW / 4;           // 4-col chunks per row
        #pragma unroll
        for (int ch = 0; ch < 32 * CPR / 64; ++ch) {
            const int c = ch * 64 + lane;
            const int lr = c / CPR, cc = (c % CPR) * 4;
            const uint2 d = *(const uint2*)&wb[lr * BSTR + cc];
            const size_t g = (size_t)(rowb + lr) * NTOT + bcol + cc;
            const ushort* rs = qsrc + g;      // residual: bf16 query (NTOT==DIMS)
            float x[4] = { bs2f((ushort)d.x) + bs2f(rs[0]),
                           bs2f((ushort)(d.x >> 16)) + bs2f(rs[1]),
                           bs2f((ushort)d.y) + bs2f(rs[2]),
                           bs2f((ushort)(d.y >> 16)) + bs2f(rs[3]) };
            if (isf) {
                *(float4*)((float*)C + g) = make_float4(x[0], x[1], x[2], x[3]);
            } else {
                uint2 o;
                o.x = ((unsigned)f2bs(x[1]) << 16) | f2bs(x[0]);
                o.y = ((unsigned)f2bs(x[3]) << 16) | f2bs(x[2]);
                *(uint2*)((ushort*)C + g) = o;
            }
        }
    }
}

// merged GEMM1 (800 blocks) + GEMM2 (400 blocks)
__global__ __launch_bounds__(256) void proj_k(
    const ushort* __restrict__ WvT, const float* __restrict__ biasv,
    ushort* __restrict__ v_ws,
    const ushort* __restrict__ WoaT, const float* __restrict__ biasoa,
    ushort* __restrict__ offraw,
    const void* __restrict__ query_raw, const void* __restrict__ voxbev_raw,
    const ushort* __restrict__ qb, const ushort* __restrict__ vbv,
    const int* __restrict__ flagp)
{
    __shared__ __align__(16) ushort bounce[4 * 32 * 136];   // 34.8 KB
    const int isf = *flagp;
    const ushort* qsrc = isf ? qb  : (const ushort*)query_raw;
    const ushort* vsrc = isf ? vbv : (const ushort*)voxbev_raw;
    if (blockIdx.x < 800)
        gemmw<A_VAL, O_BF16, 128, 256, 256>(blockIdx.x * 64, nullptr, WvT,
            biasv, (void*)v_ws, qsrc, vsrc, isf, bounce);
    else
        gemmw<A_QCAT, O_BF16, 96, 512, 192>((blockIdx.x - 800) * 64, nullptr,
            WoaT, biasoa, (void*)offraw, qsrc, vsrc, isf, bounce);
}

// GEMM4: out = sampled @ Wo + bo + residual(bf16 query)
__global__ __launch_bounds__(256) void gemm4_k(
    const ushort* __restrict__ sampled, const ushort* __restrict__ WoT,
    const float* __restrict__ biaso, void* __restrict__ C,
    const void* __restrict__ query_raw,
    const ushort* __restrict__ qb, const int* __restrict__ flagp)
{
    __shared__ __align__(16) ushort bounce[4 * 32 * 136];
    const int isf = *flagp;
    const ushort* qsrc = isf ? qb : (const ushort*)query_raw;
    gemmw<A_PLAIN, O_FINAL, 128, 256, 256>(blockIdx.x * 64, sampled, WoT,
        biaso, C, qsrc, nullptr, isf, bounce);
}

// ---------------------------------------------------------------------------
// Fused softmax + coords + bilinear sampling + queue mean. Batched gathers
// (16 outstanding loads). Block = 8 queries of ONE batch (XCD-swizzled).
// ---------------------------------------------------------------------------
__global__ __launch_bounds__(256) void sample_k(
    const ushort* __restrict__ v,        // [BS*2, NQ, 256] bf16
    const ushort* __restrict__ offraw,   // [BS*NQ, 192] bf16
    const void* __restrict__ refpts,     // [BS*2, NQ, 1, 2] input dtype
    const int* __restrict__ flagp,
    ushort* __restrict__ sampled)        // [BS*NQ, 256] bf16
{
    const int isf = *flagp;
    __shared__ float sx[8][2][8][4], sy[8][2][8][4], sw[8][2][8][4];
    const int tid = threadIdx.x;
    const int j = blockIdx.x;
    const int slot = j & 7;
    const int b = slot >> 1;
    const int idx = ((j >> 3) << 1) + (slot & 1);    // 0..799
    const int q0 = idx * 8;

    if (tid < 128) {
        const int lq = tid >> 4, queue = (tid >> 3) & 1, h = tid & 7;
        const int q = q0 + lq;
        const int gq = b * NQ + q;
        const ushort* row = offraw + (size_t)gq * 192;
        const ushort* al = row + 128 + h * 8 + queue * 4;
        float l0 = bs2f(al[0]), l1 = bs2f(al[1]), l2 = bs2f(al[2]), l3 = bs2f(al[3]);
        float mx = fmaxf(fmaxf(l0, l1), fmaxf(l2, l3));
        float e0 = __expf(l0 - mx), e1 = __expf(l1 - mx);
        float e2 = __expf(l2 - mx), e3 = __expf(l3 - mx);
        float inv = 0.5f / (e0 + e1 + e2 + e3);      // fold queue-mean 0.5
        const int bq = b * 2 + queue;
        const float rx = ldin(refpts, ((size_t)bq * NQ + q) * 2 + 0, isf);
        const float ry = ldin(refpts, ((size_t)bq * NQ + q) * 2 + 1, isf);
        const ushort* od = row + h * 16 + queue * 8;
        float ww[4] = { e0 * inv, e1 * inv, e2 * inv, e3 * inv };
        #pragma unroll
        for (int p = 0; p < NP; ++p) {
            sx[lq][queue][h][p] = rx * (float)GW + bs2f(od[p * 2 + 0]) - 0.5f;
            sy[lq][queue][h][p] = ry * (float)GH + bs2f(od[p * 2 + 1]) - 0.5f;
            sw[lq][queue][h][p] = ww[p];
        }
    }
    __syncthreads();

    const int lq = tid >> 5, h = (tid >> 2) & 7, d8 = tid & 3;
    const int gq = b * NQ + q0 + lq;
    const int doff = h * 32 + d8 * 8;
    float a[8] = {};
    #pragma unroll
    for (int queue = 0; queue < 2; ++queue) {
        const ushort* vb = v + (size_t)(b * 2 + queue) * NQ * DIMS;
        float cw[16];
        int pix[16];
        #pragma unroll
        for (int p = 0; p < NP; ++p) {
            const float x = sx[lq][queue][h][p];
            const float y = sy[lq][queue][h][p];
            const float w = sw[lq][queue][h][p];
            const float x0f = floorf(x), y0f = floorf(y);
            const float dx = x - x0f, dy = y - y0f;
            const int x0 = (int)x0f, y0 = (int)y0f;
            const float c4[4] = { w * (1.0f - dx) * (1.0f - dy),
                                  w * dx * (1.0f - dy),
                                  w * (1.0f - dx) * dy,
                                  w * dx * dy };
            #pragma unroll
            for (int c = 0; c < 4; ++c) {
                const int xs = x0 + (c & 1), ys = y0 + (c >> 1);
                const bool ok = (unsigned)xs < (unsigned)GW && (unsigned)ys < (unsigned)GH;
                const int xi = min(max(xs, 0), GW - 1);
                const int yi = min(max(ys, 0), GH - 1);
                cw[p * 4 + c] = ok ? c4[c] : 0.0f;
                pix[p * 4 + c] = yi * GW + xi;
            }
        }
        uint4 d[16];
        #pragma unroll
        for (int i = 0; i < 16; ++i)
            d[i] = *(const uint4*)&vb[(size_t)pix[i] * DIMS + doff];
        #pragma unroll
        for (int i = 0; i < 16; ++i) {
            const float c = cw[i];
            a[0] += c * bs2f((ushort)d[i].x); a[1] += c * bs2f((ushort)(d[i].x >> 16));
            a[2] += c * bs2f((ushort)d[i].y); a[3] += c * bs2f((ushort)(d[i].y >> 16));
            a[4] += c * bs2f((ushort)d[i].z); a[5] += c * bs2f((ushort)(d[i].z >> 16));
            a[6] += c * bs2f((ushort)d[i].w); a[7] += c * bs2f((ushort)(d[i].w >> 16));
        }
    }
    uint4 o;
    o.x = ((unsigned)f2bs(a[1]) << 16) | f2bs(a[0]);
    o.y = ((unsigned)f2bs(a[3]) << 16) | f2bs(a[2]);
    o.z = ((unsigned)f2bs(a[5]) << 16) | f2bs(a[4]);
    o.w = ((unsigned)f2bs(a[7]) << 16) | f2bs(a[6]);
    *(uint4*)&sampled[(size_t)gq * DIMS + doff] = o;
}

// ---------------------------------------------------------------------------
extern "C" void kernel_launch(void* const* d_in, const int* in_sizes, int n_in,
                              void* d_out, int out_size, void* d_ws, size_t ws_size,
                              hipStream_t stream)
{
    const void* query  = d_in[0];
    const void* voxbev = d_in[1];
    const void* refpts = d_in[2];
    // d_in[3] spatial_shapes=[[80,80]], d_in[4] level_start_index=[0]: hardcoded
    const void* Wv   = d_in[5];  const void* bv    = d_in[6];
    const void* Woff = d_in[7];  const void* boff  = d_in[8];
    const void* Wattn= d_in[9];  const void* battn = d_in[10];
    const void* Wo   = d_in[11]; const void* bo    = d_in[12];

    // workspace (~59.8 MB, within proven budget)
    char* p = (char*)d_ws;
    int* flag = (int*)p;             p += 256;
    ushort* WvT  = (ushort*)p;       p += 256 * 256 * 2;
    ushort* WoaT = (ushort*)p;       p += 192 * 512 * 2;
    ushort* WoT  = (ushort*)p;       p += 256 * 256 * 2;
    float* biasv  = (float*)p;       p += 1024;
    float* biasoa = (float*)p;       p += 1024;
    float* biaso  = (float*)p;       p += 1024;
    ushort* qb   = (ushort*)p;       p += (size_t)BS * NQ * DIMS * 2;       // 13.1 MB
    ushort* vbv  = (ushort*)p;       p += (size_t)BS * NQ * DIMS * 2;       // 13.1 MB
    ushort* v_ws = (ushort*)p;       p += (size_t)2 * BS * NQ * DIMS * 2;   // 26.2 MB
    ushort* offraw = (ushort*)p;     p += (size_t)BS * NQ * 192 * 2;        //  9.8 MB
    ushort* sampled = (ushort*)p;    // 13.1 MB

    // 0. self-detecting convert + weight prep (publishes dtype flag)
    prep_k<<<7299, 256, 0, stream>>>(query, voxbev, Wv, bv, Woff, boff,
                                     Wattn, battn, Wo, bo, flag,
                                     (uint4*)qb, (uint4*)vbv,
                                     WvT, WoaT, WoT, biasv, biasoa, biaso);

    // 1+2. merged: v = value @ Wv + bv  AND  offraw = qcat @ [Woff|Wattn]+bias
    proj_k<<<1200, 256, 0, stream>>>(WvT, biasv, v_ws, WoaT, biasoa, offraw,
                                     query, voxbev, qb, vbv, flag);

    // 3. fused softmax + coords + bilinear sampling + queue mean
    sample_k<<<3200, 256, 0, stream>>>(v_ws, offraw, refpts, flag, sampled);

    // 4. out = sampled @ Wo + bo + residual
    gemm4_k<<<400, 256, 0, stream>>>(sampled, WoT, biaso, d_out, query, qb, flag);
}